// Round 11
// baseline (969.470 us; speedup 1.0000x reference)
//
#include <hip/hip_runtime.h>

#define NCLS 80
#define TPOINTS 17064
#define GN_EPS 1e-5f

typedef float v4f __attribute__((ext_vector_type(4)));
typedef short v8s __attribute__((ext_vector_type(8)));

__device__ __forceinline__ unsigned short f2bf(float f) {
    unsigned u = __float_as_uint(f);
    unsigned r = (u + 0x7FFFu + ((u >> 16) & 1u)) >> 16;
    return (unsigned short)r;
}
__device__ __forceinline__ float bf2f(unsigned short h) {
    return __uint_as_float(((unsigned)h) << 16);
}
__device__ __forceinline__ void gload16(const unsigned short* g, unsigned short* l) {
    __builtin_amdgcn_global_load_lds(
        (const __attribute__((address_space(1))) unsigned int*)g,
        (__attribute__((address_space(3))) unsigned int*)l, 16, 0, 0);
}
template<int N> __device__ __forceinline__ void vwait() {
    asm volatile("s_waitcnt vmcnt(%0)" :: "n"(N) : "memory");
    __builtin_amdgcn_sched_barrier(0);
}
#define LGKM0 do { asm volatile("s_waitcnt lgkmcnt(0)" ::: "memory"); } while (0)

struct Lv { int t_conv, t_gn, t_prep, t_h5, xo, P2W, PP, HW, W, H, lwW, loff; };
struct Tab { Lv lv[5]; };

// ---------------------------------------------------------------------------
// Implicit-GEMM conv, r8 structure, DE-BURSTED half body (r11).
// r8+r10 budget: T_item=100us -> 2920 cyc/half; LDS traffic (128KB rd +
// 48KB wr per CU-half @ ~12cyc/KB) = 2112 cyc -> LDS-BW dominant, and the
// ~800cyc gap was SELF-INFLICTED: inline LGKM0+sched_barrier before the
// MFMA cluster forced full read-drain before any MFMA (read-burst/MFMA-
// burst anti-overlap). Rule 18 applies to inline-asm ds_reads; ours are
// compiler loads with fine-grained lgkmcnt. r11 half body:
//   vwait<6> -> barrier(slot ready) -> frag reads + MFMA (compiler
//   interleaves) -> LGKM0 (free; reads consumed) -> barrier(all reads
//   done) -> stage(h+3).
// Slot safety unchanged: stage strictly after all-reads-done barrier;
// deposits published by per-wave vwait before slot-ready barrier. Stage
// ~300cyc later is harmless at 3-half (~9000cyc) prefetch depth.
// r10's work stealing reverted (integer wall: 572 items/512 workers ->
// 2 rounds regardless; atomic+drain cost 16us).
// Tile 256co x 128pos, 8 waves (4co x 2pos, 64x64, acc[4][4]); 3-deep
// pipeline; LDS 72KB -> 2 blocks/CU; tail vwait 3/0; XOR chunk-swizzle.
// TOWER (HEAD=0): bf16 ci-blocked out + fused GN stats.
// HEAD=1 (z=4): br=0 cls logits cols 0-79; br=1 bbox+ctr cols 80-84.
// ---------------------------------------------------------------------------
template<int HEAD>
__global__ __launch_bounds__(512, 4) void conv_k(
    const unsigned short* __restrict__ xin, size_t xin_brs,
    const unsigned short* __restrict__ wt, size_t wt_brs, int wrows,
    const float* __restrict__ bias_c, const float* __restrict__ bias_r,
    unsigned short* __restrict__ yout, float* __restrict__ stats, int layer,
    float* __restrict__ out,
    Tab tb)
{
    __shared__ __align__(16) unsigned short sA[3 * 256 * 32];   // 48KB
    __shared__ __align__(16) unsigned short sB[3 * 128 * 32];   // 24KB
    const int tid = threadIdx.x, lane = tid & 63, wave = tid >> 6;
    const int bx = blockIdx.x, z = blockIdx.z;
    const int n = z & 1, br = z >> 1;
    int L = 0;
    while (L < 4 && bx >= tb.lv[L + 1].t_conv) ++L;
    const Lv lv = tb.lv[L];
    const int pp0 = (bx - lv.t_conv) * 128;
    const size_t XELs = 9200640;
    const size_t PP32 = (size_t)lv.PP * 32;

    v4f acc[4][4];
#pragma unroll
    for (int i = 0; i < 4; ++i)
#pragma unroll
        for (int j = 0; j < 4; ++j) acc[i][j] = (v4f)0.f;

    const unsigned short* wtb = wt + (size_t)br * wt_brs;
    const float* bias = br ? bias_r : bias_c;
    const unsigned short* xb = xin + (size_t)br * xin_brs +
                               (size_t)lv.xo + (size_t)n * lv.PP * 256;

    // staging: A: wave w rows [w*32, +32) of 256; B: wave w rows [w*16, +16)
    // of 128. lane l -> row += l>>2, source chunk (l&3)^((l>>3)&3) (LDS holds
    // row-XOR-swizzled chunks; == chunk ^ ((row>>1)&3) for 16-row groups).
    const int lr = lane >> 2;
    const int lc = ((lane & 3) ^ ((lane >> 3) & 3)) * 8;
    const unsigned short* ag = wtb + (size_t)(wave * 32 + lr) * 32 + lc;
    const unsigned short* bgh = xb + (ptrdiff_t)(pp0 + wave * 16 + lr) * 32 + lc;
    unsigned short* laW = &sA[wave * 32 * 32];
    unsigned short* lbW = &sB[wave * 16 * 32];
    const size_t wstride2 = (size_t)wrows * 32;   // elems per K-half A tile

    const int col = lane & 15, q = lane >> 4;
    const int wr = wave & 3, wc = wave >> 2;      // 4 co-blocks x 2 pos-blocks
    const int qs = (q ^ ((col >> 1) & 3)) << 3;
    int ard[4], brd[4];
#pragma unroll
    for (int i = 0; i < 4; ++i) ard[i] = (wr * 64 + i * 16 + col) * 32 + qs;
#pragma unroll
    for (int j = 0; j < 4; ++j) brd[j] = (wc * 64 + j * 16 + col) * 32 + qs;

    auto stageHalf = [&](int s) {
        const int slot = s % 3;
        const unsigned short* at = ag + (size_t)s * wstride2;
        gload16(at,       laW + slot * 8192);
        gload16(at + 512, laW + slot * 8192 + 512);
        const int t = s >> 3, kb = s & 7;
        const ptrdiff_t goff = ((ptrdiff_t)(t / 3) - 1) * lv.P2W + (t % 3) - 1;
        gload16(bgh + (size_t)kb * PP32 + goff * 32, lbW + slot * 4096);
    };

    auto half_body = [&](int h, bool dostage) {
        const int sa = (h % 3) * 8192, sb_ = (h % 3) * 4096;
        v8s af[4], bfr[4];
#pragma unroll
        for (int i = 0; i < 4; ++i) af[i]  = *(const v8s*)&sA[sa + ard[i]];
#pragma unroll
        for (int j = 0; j < 4; ++j) bfr[j] = *(const v8s*)&sB[sb_ + brd[j]];
        // compiler interleaves these reads with the MFMAs via counted lgkmcnt
        __builtin_amdgcn_s_setprio(1);
#pragma unroll
        for (int i = 0; i < 4; ++i)
#pragma unroll
            for (int j = 0; j < 4; ++j)
                acc[i][j] = __builtin_amdgcn_mfma_f32_16x16x32_bf16(
                    af[i], bfr[j], acc[i][j], 0, 0, 0);
        __builtin_amdgcn_s_setprio(0);
        LGKM0;                                   // free: reads consumed above
        __builtin_amdgcn_s_barrier();            // all waves done w/ slot h%3
        __builtin_amdgcn_sched_barrier(0);
        if (dostage) stageHalf(h + 3);           // slot (h+3)%3 == h%3 free
    };

    // prologue: halves 0,1,2 in flight (9 gloads/wave, 3 per half)
    stageHalf(0); stageHalf(1); stageHalf(2);
#pragma unroll 1
    for (int h = 0; h < 70; ++h) {
        if (h < 70) vwait<6>();              // own 3 of half h retired
        __builtin_amdgcn_s_barrier();        // all waves: half h staged
        __builtin_amdgcn_sched_barrier(0);
        half_body(h, h < 69);
    }
    vwait<3>(); __builtin_amdgcn_s_barrier(); __builtin_amdgcn_sched_barrier(0);
    half_body(70, false);
    vwait<0>(); __builtin_amdgcn_s_barrier(); __builtin_amdgcn_sched_barrier(0);
    half_body(71, false);

    if (!HEAD) {
        unsigned short* yb = yout + (size_t)br * XELs + (size_t)lv.xo +
                             (size_t)n * lv.PP * 256;
        const int slot = br * 3 + layer;
#pragma unroll
        for (int i = 0; i < 4; ++i) {
            const int cobase = wr * 64 + i * 16 + q * 4;
            const float4 b4 = *(const float4*)(bias + cobase);
            const size_t kbo = (size_t)(cobase >> 5) * PP32;
            const int cc = cobase & 31;
            float s = 0.f, ss = 0.f;
#pragma unroll
            for (int j = 0; j < 4; ++j) {
                const int pp = pp0 + wc * 64 + j * 16 + col;
                const unsigned h2 = (unsigned)pp / (unsigned)lv.P2W;
                const unsigned w2 = (unsigned)pp - h2 * lv.P2W;
                const bool in = (h2 >= 1u) & (h2 <= (unsigned)lv.H) &
                                (w2 >= 1u) & (w2 <= (unsigned)lv.W);
                float v0 = acc[i][j][0] + b4.x;
                float v1 = acc[i][j][1] + b4.y;
                float v2 = acc[i][j][2] + b4.z;
                float v3 = acc[i][j][3] + b4.w;
                if (in) {
                    ushort4 pk;
                    pk.x = f2bf(v0); pk.y = f2bf(v1);
                    pk.z = f2bf(v2); pk.w = f2bf(v3);
                    *(ushort4*)(yb + kbo + (size_t)pp * 32 + cc) = pk;
                    s  += v0 + v1 + v2 + v3;
                    ss += v0 * v0 + v1 * v1 + v2 * v2 + v3 * v3;
                }
            }
#pragma unroll
            for (int o = 32; o > 0; o >>= 1) {
                s  += __shfl_down(s, o, 64);
                ss += __shfl_down(ss, o, 64);
            }
            if (lane == 0) {
                const int g = cobase >> 4;
                const int si = (((slot * 5 + L) * 32) + n * 16 + g) * 2;
                atomicAdd(&stats[si + 0], s);
                atomicAdd(&stats[si + 1], ss);
            }
        }
    } else {
        // br=0: cls logits from B1[0], CO=80, cols 0..79, no relu.
        // br=1: bbox+ctr from B1[1], CO=5, cols 80..84, relu co<4.
        const int CO_ = br ? 5 : 80;
        const int coo = br ? 80 : 0;
        const int rel = br ? 4 : 0;
#pragma unroll
        for (int i = 0; i < 4; ++i) {
            const int cobase = wr * 64 + i * 16 + q * 4;
            float bv[4];
#pragma unroll
            for (int k = 0; k < 4; ++k)
                bv[k] = (cobase + k < CO_) ? bias[cobase + k] : 0.f;
#pragma unroll
            for (int j = 0; j < 4; ++j) {
                const int pp = pp0 + wc * 64 + j * 16 + col;
                const unsigned h2 = (unsigned)pp / (unsigned)lv.P2W;
                const unsigned w2 = (unsigned)pp - h2 * lv.P2W;
                const bool in = (h2 >= 1u) & (h2 <= (unsigned)lv.H) &
                                (w2 >= 1u) & (w2 <= (unsigned)lv.W);
                if (in) {
                    const int p = (h2 - 1) * lv.W + (w2 - 1);
                    float* ob = out + ((size_t)n * TPOINTS + lv.loff + p) * 85 + coo;
#pragma unroll
                    for (int k = 0; k < 4; ++k) {
                        const int co = cobase + k;
                        if (co < CO_) {
                            float v = acc[i][j][k] + bv[k];
                            if (co < rel) v = fmaxf(v, 0.f);
                            ob[co] = v;
                        }
                    }
                }
            }
        }
    }
}

// ---------------------------------------------------------------------------
// GN + affine + ReLU, in-place, fused across levels AND branches (z=br*2+n).
// ---------------------------------------------------------------------------
__global__ __launch_bounds__(256) void gn_k(
    unsigned short* __restrict__ x, const float* __restrict__ stats, int layer,
    const float* __restrict__ g_c, const float* __restrict__ be_c,
    const float* __restrict__ g_r, const float* __restrict__ be_r, Tab tb)
{
    const int tid = threadIdx.x, bx = blockIdx.x, z = blockIdx.z;
    const int n = z & 1, br = z >> 1;
    const size_t XELs = 9200640;
    int L = 0;
    while (L < 4 && bx >= tb.lv[L + 1].t_gn) ++L;
    const Lv lv = tb.lv[L];
    const int pos = (bx - lv.t_gn) * 32 + (tid >> 3);
    if (pos >= lv.HW) return;
    const int slot = br * 3 + layer;
    const float* gamma = (br ? g_r : g_c) + layer * 256;
    const float* beta  = (br ? be_r : be_c) + layer * 256;
    const int c0 = (tid & 7) * 32;
    const int h = pos >> lv.lwW, w = pos & (lv.W - 1);
    const int pp = (h + 1) * lv.P2W + (w + 1);
    unsigned short* p = x + (size_t)br * XELs + (size_t)lv.xo +
                        (size_t)n * lv.PP * 256 +
                        (size_t)(tid & 7) * lv.PP * 32 + (size_t)pp * 32;
    const float inv = 1.0f / (16.0f * (float)lv.HW);
    const int sb = ((slot * 5 + L) * 32 + n * 16) * 2;

    float scv[32], shv[32];
#pragma unroll
    for (int gg = 0; gg < 2; ++gg) {
        const int g = (c0 >> 4) + gg;
        const float mm = stats[sb + g * 2 + 0] * inv;
        const float v = stats[sb + g * 2 + 1] * inv - mm * mm;
        const float rs = rsqrtf(v + GN_EPS);
#pragma unroll
        for (int k = 0; k < 16; ++k) {
            const int c = g * 16 + k;
            const float sc = rs * gamma[c];
            scv[gg * 16 + k] = sc;
            shv[gg * 16 + k] = beta[c] - mm * sc;
        }
    }
#pragma unroll
    for (int u = 0; u < 4; ++u) {
        uint4 a = *(const uint4*)(p + u * 8);
        unsigned wds[4] = {a.x, a.y, a.z, a.w};
#pragma unroll
        for (int k = 0; k < 4; ++k) {
            const int e = u * 8 + k * 2;
            float lo = bf2f((unsigned short)(wds[k] & 0xffffu));
            float hi = bf2f((unsigned short)(wds[k] >> 16));
            lo = fmaxf(lo * scv[e]     + shv[e],     0.f);
            hi = fmaxf(hi * scv[e + 1] + shv[e + 1], 0.f);
            wds[k] = (unsigned)f2bf(lo) | ((unsigned)f2bf(hi) << 16);
        }
        uint4 o; o.x = wds[0]; o.y = wds[1]; o.z = wds[2]; o.w = wds[3];
        *(uint4*)(p + u * 8) = o;
    }
}

// ---------------------------------------------------------------------------
// fp32 NCHW feats -> bf16 ci-blocked padded interior.
// ---------------------------------------------------------------------------
__global__ __launch_bounds__(256) void prepx_k(
    const float* f0, const float* f1, const float* f2, const float* f3,
    const float* f4, unsigned short* __restrict__ xo, Tab tb)
{
    const float* fs[5] = {f0, f1, f2, f3, f4};
    const int tid = threadIdx.x, bx = blockIdx.x, n = blockIdx.z;
    int L = 0;
    while (L < 4 && bx >= tb.lv[L + 1].t_prep) ++L;
    const Lv lv = tb.lv[L];
    const int pos = (bx - lv.t_prep) * 64 + (tid & 63);
    const int wave = tid >> 6;
    if (pos >= lv.HW) return;
    const int h = pos >> lv.lwW, w = pos & (lv.W - 1);
    const int pp = (h + 1) * lv.P2W + (w + 1);
    const float* src = fs[L] + (size_t)n * 256 * lv.HW + pos;
    unsigned short* dst = xo + (size_t)lv.xo + (size_t)n * lv.PP * 256;
#pragma unroll
    for (int k = 0; k < 16; ++k) {
        const int c = wave * 64 + k * 4;
        ushort4 pk;
        pk.x = f2bf(src[(size_t)(c + 0) * lv.HW]);
        pk.y = f2bf(src[(size_t)(c + 1) * lv.HW]);
        pk.z = f2bf(src[(size_t)(c + 2) * lv.HW]);
        pk.w = f2bf(src[(size_t)(c + 3) * lv.HW]);
        *(ushort4*)(dst + (size_t)(c >> 5) * lv.PP * 32 +
                    (size_t)pp * 32 + (c & 31)) = pk;
    }
}

// ---------------------------------------------------------------------------
// tower weights: [br][layer][tap][kb][co 256][32ci]. r11: COALESCED — one
// thread per (br,layer,co,ci) reads its 9 taps contiguously (36B/thread,
// wave reads a dense 2.3KB window; was a stride-36B gather using 4B/line).
__global__ __launch_bounds__(256) void prepwt_k(
    const float* __restrict__ cw, const float* __restrict__ rw,
    unsigned short* __restrict__ dst)
{
    const int idx = blockIdx.x * 256 + threadIdx.x;   // 2*3*256*256 threads
    const int ci = idx & 255, co = (idx >> 8) & 255;
    const int lyr = (idx >> 16) % 3, br = idx / (65536 * 3);
    const float* s = br ? rw : cw;
    const float* sp = s + (((size_t)lyr * 256 + co) * 256 + ci) * 9;
    float v[9];
#pragma unroll
    for (int t = 0; t < 9; ++t) v[t] = sp[t];
    unsigned short* dp = dst + ((size_t)br * 27 + lyr * 9) * 65536 +
                         (size_t)(((ci >> 5) * 256 + co) * 32) + (ci & 31);
#pragma unroll
    for (int t = 0; t < 9; ++t) dp[(size_t)t * 65536] = f2bf(v[t]);
}

// head weights: [tap][kb][co rows][32ci], rows=256 (zero-padded planes)
__global__ __launch_bounds__(256) void prepwh_k(
    const float* __restrict__ src, unsigned short* __restrict__ dst,
    int CO, int rows, int roff)
{
    const int idx = blockIdx.x * 256 + threadIdx.x;
    if (idx >= CO * 2304) return;
    const int ci = idx & 255, rr = idx >> 8;
    const int tap = rr % 9, co = rr / 9;
    dst[((size_t)(tap * 8 + (ci >> 5)) * rows + roff + co) * 32 + (ci & 31)] =
        f2bf(src[((size_t)co * 256 + ci) * 9 + tap]);
}

// ---------------------------------------------------------------------------
extern "C" void kernel_launch(void* const* d_in, const int* in_sizes, int n_in,
                              void* d_out, int out_size, void* d_ws, size_t ws_size,
                              hipStream_t stream) {
    const float* f0 = (const float*)d_in[0];
    const float* f1 = (const float*)d_in[1];
    const float* f2 = (const float*)d_in[2];
    const float* f3 = (const float*)d_in[3];
    const float* f4 = (const float*)d_in[4];
    const float* cls_w  = (const float*)d_in[5];
    const float* cls_b  = (const float*)d_in[6];
    const float* cls_g  = (const float*)d_in[7];
    const float* cls_be = (const float*)d_in[8];
    const float* log_w  = (const float*)d_in[9];
    const float* log_b  = (const float*)d_in[10];
    const float* reg_w  = (const float*)d_in[11];
    const float* reg_b  = (const float*)d_in[12];
    const float* reg_g  = (const float*)d_in[13];
    const float* reg_be = (const float*)d_in[14];
    const float* bbox_w = (const float*)d_in[15];
    const float* bbox_b = (const float*)d_in[16];
    const float* ctr_w  = (const float*)d_in[17];
    const float* ctr_b  = (const float*)d_in[18];
    float* out = (float*)d_out;

    Tab tb;
    // t_conv: 128-pos tiles over PADDED pp space: ceil(PP/128) =
    // 104,27,8,3,1 -> cum 0,104,131,139,142 (NT=143).
    //            t_conv t_gn t_prep t_h5 xo       P2W  PP     HW     W    H   lwW loff
    tb.lv[0] = {   0,    0,    0,    0,   0,       130, 13260, 12800, 128, 100, 7, 0     };
    tb.lv[1] = { 104,  400,  200,  52,  6789120,    66,  3432,  3200,  64,  50, 6, 12800 };
    tb.lv[2] = { 131,  500,  250,  66,  8546304,    34,   918,   800,  32,  25, 5, 16000 };
    tb.lv[3] = { 139,  525,  263,  70,  9016320,    18,   270,   208,  16,  13, 4, 16800 };
    tb.lv[4] = { 142,  532,  267,  72,  9154560,    10,    90,    56,   8,   7, 3, 17008 };
    const int NT_CONV = 143, NT_GN = 534, NT_PREP = 268;
    const size_t XEL = 9200640;
    const size_t WHP = (size_t)72 * 256 * 32;     // one 256-row head weight plane

    char* base = (char*)d_ws;
    size_t o = 0;
    auto take = [&](size_t bytes) {
        char* p = base + o; o += (bytes + 255) & ~(size_t)255; return p;
    };
    take(131072);                                        // guard 128KB
    unsigned short* PX = (unsigned short*)take(XEL * 2);          // shared input
    take(131072);
    unsigned short* B1 = (unsigned short*)take(XEL * 2 * 2);      // [br]
    take(131072);
    unsigned short* B2 = (unsigned short*)take(XEL * 2 * 2);      // [br]
    take(131072);
    unsigned short* WT = (unsigned short*)take((size_t)54 * 65536 * 2);
    unsigned short* WH = (unsigned short*)take(WHP * 2 * 2);      // [br] planes
    float* ST  = (float*)take(1920 * 4);
    float* RB5 = (float*)take(32);

    hipMemsetAsync(PX, 0, XEL * 2, stream);
    hipMemsetAsync(B1, 0, XEL * 4, stream);
    hipMemsetAsync(B2, 0, XEL * 4, stream);
    hipMemsetAsync(ST, 0, 1920 * 4, stream);
    hipMemsetAsync(WH, 0, WHP * 2 * 2, stream);
    hipMemcpyAsync(RB5,     bbox_b, 4 * 4, hipMemcpyDeviceToDevice, stream);
    hipMemcpyAsync(RB5 + 4, ctr_b,  1 * 4, hipMemcpyDeviceToDevice, stream);

    prepwt_k<<<dim3(1536), dim3(256), 0, stream>>>(cls_w, reg_w, WT);
    prepwh_k<<<dim3(720), dim3(256), 0, stream>>>(log_w,  WH,       80, 256, 0);
    prepwh_k<<<dim3(36),  dim3(256), 0, stream>>>(bbox_w, WH + WHP,  4, 256, 0);
    prepwh_k<<<dim3(9),   dim3(256), 0, stream>>>(ctr_w,  WH + WHP,  1, 256, 4);

    prepx_k<<<dim3(NT_PREP, 1, 2), dim3(256), 0, stream>>>(f0, f1, f2, f3, f4, PX, tb);

    // chain: conv0 PX->B1[br], gn0 B1; conv1 B1->B2, gn1 B2; conv2 B2->B1,
    // gn2 B1; fused head (z=4): br=0 cls from B1[0], br=1 bbox+ctr from B1[1].
    const size_t WBRS = (size_t)27 * 65536;
    unsigned short* cin[3]  = {PX, B1, B2};
    size_t          cbrs[3] = {0, XEL, XEL};
    unsigned short* cout_[3] = {B1, B2, B1};
    for (int i = 0; i < 3; ++i) {
        conv_k<0><<<dim3(NT_CONV, 1, 4), dim3(512), 0, stream>>>(
            cin[i], cbrs[i], WT + (size_t)i * 9 * 65536, WBRS, 256,
            cls_b + i * 256, reg_b + i * 256,
            cout_[i], ST, i, nullptr, tb);
        gn_k<<<dim3(NT_GN, 1, 4), dim3(256), 0, stream>>>(
            cout_[i], ST, i, cls_g, cls_be, reg_g, reg_be, tb);
    }
    conv_k<1><<<dim3(NT_CONV, 1, 4), dim3(512), 0, stream>>>(
        B1, XEL, WH, WHP, 256, log_b, RB5,
        nullptr, nullptr, 0, out, tb);
}

// Round 12
// 901.040 us; speedup vs baseline: 1.0759x; 1.0759x over previous
//
#include <hip/hip_runtime.h>

#define NCLS 80
#define TPOINTS 17064
#define GN_EPS 1e-5f

typedef float v4f __attribute__((ext_vector_type(4)));
typedef short v8s __attribute__((ext_vector_type(8)));

__device__ __forceinline__ unsigned short f2bf(float f) {
    unsigned u = __float_as_uint(f);
    unsigned r = (u + 0x7FFFu + ((u >> 16) & 1u)) >> 16;
    return (unsigned short)r;
}
__device__ __forceinline__ float bf2f(unsigned short h) {
    return __uint_as_float(((unsigned)h) << 16);
}
__device__ __forceinline__ void gload16(const unsigned short* g, unsigned short* l) {
    __builtin_amdgcn_global_load_lds(
        (const __attribute__((address_space(1))) unsigned int*)g,
        (__attribute__((address_space(3))) unsigned int*)l, 16, 0, 0);
}
template<int N> __device__ __forceinline__ void vwait() {
    asm volatile("s_waitcnt vmcnt(%0)" :: "n"(N) : "memory");
    __builtin_amdgcn_sched_barrier(0);
}
#define LGKM0 do { asm volatile("s_waitcnt lgkmcnt(0)" ::: "memory"); \
                   __builtin_amdgcn_sched_barrier(0); } while (0)

struct Lv { int t_conv, t_gn, t_prep, t_h5, xo, P2W, PP, HW, W, H, lwW, loff; };
struct Tab { Lv lv[5]; };

// ---------------------------------------------------------------------------
// Implicit-GEMM conv (r12): r8 structure, FAT WAVES (128co x 64pos each).
// r9/r10/r11 all regressed vs r8's 201us -> r8 order restored verbatim.
// r8 issue-budget: per wave-half 8 ds_read_b128 (~96cyc) + 16 MFMA (~80)
// x4 waves/SIMD ~ 930cyc vs 1120 period -> SIMD ISSUE PORT ~85% saturated,
// ds_read dominant. Fragment reads scale (M+N)K, MFMA MNK: 128x64 wave
// tile = 12 b128 / 32 MFMA (384B/MFMA) vs 64x64's 8/16 (512B/MFMA) ->
// -25% ds issue at SAME block tile (256co x 128pos), SAME LDS (72KB),
// SAME item count (572). 4 waves x 256 thr; wr=wave&1 (co half),
// wc=wave>>1 (pos half); acc[8][4]=128 AGPR (~190 regs, 2 waves/SIMD,
// launch_bounds(256,2)); 2 blocks/CU (LDS-capped) = 8 waves/CU.
// Staging/half per wave: 4 A-gloads (64 rows) + 2 B-gloads (32 rows) = 6,
// uniform -> ledger vwait<12> main, <6>/<0> tail. Half body = r8 order:
// reads -> LGKM0 -> barrier (slot free) -> stage h+3 -> setprio + MFMA.
// XOR chunk-swizzle deposit/read (0 conflicts; 16-row groups preserved).
// TOWER (HEAD=0): bf16 ci-blocked out + fused GN stats.
// HEAD=1 (z=4): br=0 cls logits cols 0-79; br=1 bbox+ctr cols 80-84.
// ---------------------------------------------------------------------------
template<int HEAD>
__global__ __launch_bounds__(256, 2) void conv_k(
    const unsigned short* __restrict__ xin, size_t xin_brs,
    const unsigned short* __restrict__ wt, size_t wt_brs, int wrows,
    const float* __restrict__ bias_c, const float* __restrict__ bias_r,
    unsigned short* __restrict__ yout, float* __restrict__ stats, int layer,
    float* __restrict__ out,
    Tab tb)
{
    __shared__ __align__(16) unsigned short sA[3 * 256 * 32];   // 48KB
    __shared__ __align__(16) unsigned short sB[3 * 128 * 32];   // 24KB
    const int tid = threadIdx.x, lane = tid & 63, wave = tid >> 6;
    const int bx = blockIdx.x, z = blockIdx.z;
    const int n = z & 1, br = z >> 1;
    int L = 0;
    while (L < 4 && bx >= tb.lv[L + 1].t_conv) ++L;
    const Lv lv = tb.lv[L];
    const int pp0 = (bx - lv.t_conv) * 128;
    const size_t XELs = 9200640;
    const size_t PP32 = (size_t)lv.PP * 32;

    v4f acc[8][4];
#pragma unroll
    for (int i = 0; i < 8; ++i)
#pragma unroll
        for (int j = 0; j < 4; ++j) acc[i][j] = (v4f)0.f;

    const unsigned short* wtb = wt + (size_t)br * wt_brs;
    const float* bias = br ? bias_r : bias_c;
    const unsigned short* xb = xin + (size_t)br * xin_brs +
                               (size_t)lv.xo + (size_t)n * lv.PP * 256;

    // staging: A: wave w rows [w*64, +64) of 256 (4 gloads of 16 rows);
    // B: wave w rows [w*32, +32) of 128 (2 gloads). lane l -> row += l>>2,
    // source chunk (l&3)^((l>>3)&3) (LDS holds row-XOR-swizzled chunks;
    // == chunk ^ ((row>>1)&3) within each 16-row group).
    const int lr = lane >> 2;
    const int lc = ((lane & 3) ^ ((lane >> 3) & 3)) * 8;
    const unsigned short* ag = wtb + (size_t)(wave * 64 + lr) * 32 + lc;
    const unsigned short* bgh = xb + (ptrdiff_t)(pp0 + wave * 32 + lr) * 32 + lc;
    unsigned short* laW = &sA[wave * 64 * 32];
    unsigned short* lbW = &sB[wave * 32 * 32];
    const size_t wstride2 = (size_t)wrows * 32;   // elems per K-half A tile

    const int col = lane & 15, q = lane >> 4;
    const int wr = wave & 1, wc = wave >> 1;      // 2 co-halves x 2 pos-halves
    const int qs = (q ^ ((col >> 1) & 3)) << 3;
    int ard[8], brd[4];
#pragma unroll
    for (int i = 0; i < 8; ++i) ard[i] = (wr * 128 + i * 16 + col) * 32 + qs;
#pragma unroll
    for (int j = 0; j < 4; ++j) brd[j] = (wc * 64 + j * 16 + col) * 32 + qs;

    auto stageHalf = [&](int s) {
        const int slot = s % 3;
        const unsigned short* at = ag + (size_t)s * wstride2;
        gload16(at,        laW + slot * 8192);
        gload16(at + 512,  laW + slot * 8192 + 512);
        gload16(at + 1024, laW + slot * 8192 + 1024);
        gload16(at + 1536, laW + slot * 8192 + 1536);
        const int t = s >> 3, kb = s & 7;
        const ptrdiff_t goff = ((ptrdiff_t)(t / 3) - 1) * lv.P2W + (t % 3) - 1;
        const unsigned short* bt = bgh + (size_t)kb * PP32 + goff * 32;
        gload16(bt,       lbW + slot * 4096);
        gload16(bt + 512, lbW + slot * 4096 + 512);
    };

    auto half_body = [&](int h, bool dostage) {
        const int sa = (h % 3) * 8192, sb_ = (h % 3) * 4096;
        v8s af[8], bfr[4];
#pragma unroll
        for (int i = 0; i < 8; ++i) af[i]  = *(const v8s*)&sA[sa + ard[i]];
#pragma unroll
        for (int j = 0; j < 4; ++j) bfr[j] = *(const v8s*)&sB[sb_ + brd[j]];
        LGKM0;                                   // frags in regs
        __builtin_amdgcn_s_barrier();            // all waves done w/ slot
        if (dostage) stageHalf(h + 3);           // slot (h+3)%3 == h%3
        __builtin_amdgcn_sched_barrier(0);
        __builtin_amdgcn_s_setprio(1);
#pragma unroll
        for (int i = 0; i < 8; ++i)
#pragma unroll
            for (int j = 0; j < 4; ++j)
                acc[i][j] = __builtin_amdgcn_mfma_f32_16x16x32_bf16(
                    af[i], bfr[j], acc[i][j], 0, 0, 0);
        __builtin_amdgcn_s_setprio(0);
    };

    // prologue: halves 0,1,2 in flight (18 gloads/wave, 6 per half)
    stageHalf(0); stageHalf(1); stageHalf(2);
#pragma unroll 1
    for (int h = 0; h < 70; ++h) {
        vwait<12>();                         // own 6 of half h retired
        __builtin_amdgcn_s_barrier();        // all waves: half h complete
        half_body(h, h < 69);
    }
    vwait<6>(); __builtin_amdgcn_s_barrier(); half_body(70, false);
    vwait<0>(); __builtin_amdgcn_s_barrier(); half_body(71, false);

    if (!HEAD) {
        unsigned short* yb = yout + (size_t)br * XELs + (size_t)lv.xo +
                             (size_t)n * lv.PP * 256;
        const int slot = br * 3 + layer;
#pragma unroll
        for (int i = 0; i < 8; ++i) {
            const int cobase = wr * 128 + i * 16 + q * 4;
            const float4 b4 = *(const float4*)(bias + cobase);
            const size_t kbo = (size_t)(cobase >> 5) * PP32;
            const int cc = cobase & 31;
            float s = 0.f, ss = 0.f;
#pragma unroll
            for (int j = 0; j < 4; ++j) {
                const int pp = pp0 + wc * 64 + j * 16 + col;
                const unsigned h2 = (unsigned)pp / (unsigned)lv.P2W;
                const unsigned w2 = (unsigned)pp - h2 * lv.P2W;
                const bool in = (h2 >= 1u) & (h2 <= (unsigned)lv.H) &
                                (w2 >= 1u) & (w2 <= (unsigned)lv.W);
                float v0 = acc[i][j][0] + b4.x;
                float v1 = acc[i][j][1] + b4.y;
                float v2 = acc[i][j][2] + b4.z;
                float v3 = acc[i][j][3] + b4.w;
                if (in) {
                    ushort4 pk;
                    pk.x = f2bf(v0); pk.y = f2bf(v1);
                    pk.z = f2bf(v2); pk.w = f2bf(v3);
                    *(ushort4*)(yb + kbo + (size_t)pp * 32 + cc) = pk;
                    s  += v0 + v1 + v2 + v3;
                    ss += v0 * v0 + v1 * v1 + v2 * v2 + v3 * v3;
                }
            }
#pragma unroll
            for (int o = 32; o > 0; o >>= 1) {
                s  += __shfl_down(s, o, 64);
                ss += __shfl_down(ss, o, 64);
            }
            if (lane == 0) {
                const int g = cobase >> 4;
                const int si = (((slot * 5 + L) * 32) + n * 16 + g) * 2;
                atomicAdd(&stats[si + 0], s);
                atomicAdd(&stats[si + 1], ss);
            }
        }
    } else {
        // br=0: cls logits from B1[0], CO=80, cols 0..79, no relu.
        // br=1: bbox+ctr from B1[1], CO=5, cols 80..84, relu co<4.
        const int CO_ = br ? 5 : 80;
        const int coo = br ? 80 : 0;
        const int rel = br ? 4 : 0;
#pragma unroll
        for (int i = 0; i < 8; ++i) {
            const int cobase = wr * 128 + i * 16 + q * 4;
            float bv[4];
#pragma unroll
            for (int k = 0; k < 4; ++k)
                bv[k] = (cobase + k < CO_) ? bias[cobase + k] : 0.f;
#pragma unroll
            for (int j = 0; j < 4; ++j) {
                const int pp = pp0 + wc * 64 + j * 16 + col;
                const unsigned h2 = (unsigned)pp / (unsigned)lv.P2W;
                const unsigned w2 = (unsigned)pp - h2 * lv.P2W;
                const bool in = (h2 >= 1u) & (h2 <= (unsigned)lv.H) &
                                (w2 >= 1u) & (w2 <= (unsigned)lv.W);
                if (in) {
                    const int p = (h2 - 1) * lv.W + (w2 - 1);
                    float* ob = out + ((size_t)n * TPOINTS + lv.loff + p) * 85 + coo;
#pragma unroll
                    for (int k = 0; k < 4; ++k) {
                        const int co = cobase + k;
                        if (co < CO_) {
                            float v = acc[i][j][k] + bv[k];
                            if (co < rel) v = fmaxf(v, 0.f);
                            ob[co] = v;
                        }
                    }
                }
            }
        }
    }
}

// ---------------------------------------------------------------------------
// GN + affine + ReLU, in-place, fused across levels AND branches (z=br*2+n).
// ---------------------------------------------------------------------------
__global__ __launch_bounds__(256) void gn_k(
    unsigned short* __restrict__ x, const float* __restrict__ stats, int layer,
    const float* __restrict__ g_c, const float* __restrict__ be_c,
    const float* __restrict__ g_r, const float* __restrict__ be_r, Tab tb)
{
    const int tid = threadIdx.x, bx = blockIdx.x, z = blockIdx.z;
    const int n = z & 1, br = z >> 1;
    const size_t XELs = 9200640;
    int L = 0;
    while (L < 4 && bx >= tb.lv[L + 1].t_gn) ++L;
    const Lv lv = tb.lv[L];
    const int pos = (bx - lv.t_gn) * 32 + (tid >> 3);
    if (pos >= lv.HW) return;
    const int slot = br * 3 + layer;
    const float* gamma = (br ? g_r : g_c) + layer * 256;
    const float* beta  = (br ? be_r : be_c) + layer * 256;
    const int c0 = (tid & 7) * 32;
    const int h = pos >> lv.lwW, w = pos & (lv.W - 1);
    const int pp = (h + 1) * lv.P2W + (w + 1);
    unsigned short* p = x + (size_t)br * XELs + (size_t)lv.xo +
                        (size_t)n * lv.PP * 256 +
                        (size_t)(tid & 7) * lv.PP * 32 + (size_t)pp * 32;
    const float inv = 1.0f / (16.0f * (float)lv.HW);
    const int sb = ((slot * 5 + L) * 32 + n * 16) * 2;

    float scv[32], shv[32];
#pragma unroll
    for (int gg = 0; gg < 2; ++gg) {
        const int g = (c0 >> 4) + gg;
        const float mm = stats[sb + g * 2 + 0] * inv;
        const float v = stats[sb + g * 2 + 1] * inv - mm * mm;
        const float rs = rsqrtf(v + GN_EPS);
#pragma unroll
        for (int k = 0; k < 16; ++k) {
            const int c = g * 16 + k;
            const float sc = rs * gamma[c];
            scv[gg * 16 + k] = sc;
            shv[gg * 16 + k] = beta[c] - mm * sc;
        }
    }
#pragma unroll
    for (int u = 0; u < 4; ++u) {
        uint4 a = *(const uint4*)(p + u * 8);
        unsigned wds[4] = {a.x, a.y, a.z, a.w};
#pragma unroll
        for (int k = 0; k < 4; ++k) {
            const int e = u * 8 + k * 2;
            float lo = bf2f((unsigned short)(wds[k] & 0xffffu));
            float hi = bf2f((unsigned short)(wds[k] >> 16));
            lo = fmaxf(lo * scv[e]     + shv[e],     0.f);
            hi = fmaxf(hi * scv[e + 1] + shv[e + 1], 0.f);
            wds[k] = (unsigned)f2bf(lo) | ((unsigned)f2bf(hi) << 16);
        }
        uint4 o; o.x = wds[0]; o.y = wds[1]; o.z = wds[2]; o.w = wds[3];
        *(uint4*)(p + u * 8) = o;
    }
}

// ---------------------------------------------------------------------------
// fp32 NCHW feats -> bf16 ci-blocked padded interior.
// ---------------------------------------------------------------------------
__global__ __launch_bounds__(256) void prepx_k(
    const float* f0, const float* f1, const float* f2, const float* f3,
    const float* f4, unsigned short* __restrict__ xo, Tab tb)
{
    const float* fs[5] = {f0, f1, f2, f3, f4};
    const int tid = threadIdx.x, bx = blockIdx.x, n = blockIdx.z;
    int L = 0;
    while (L < 4 && bx >= tb.lv[L + 1].t_prep) ++L;
    const Lv lv = tb.lv[L];
    const int pos = (bx - lv.t_prep) * 64 + (tid & 63);
    const int wave = tid >> 6;
    if (pos >= lv.HW) return;
    const int h = pos >> lv.lwW, w = pos & (lv.W - 1);
    const int pp = (h + 1) * lv.P2W + (w + 1);
    const float* src = fs[L] + (size_t)n * 256 * lv.HW + pos;
    unsigned short* dst = xo + (size_t)lv.xo + (size_t)n * lv.PP * 256;
#pragma unroll
    for (int k = 0; k < 16; ++k) {
        const int c = wave * 64 + k * 4;
        ushort4 pk;
        pk.x = f2bf(src[(size_t)(c + 0) * lv.HW]);
        pk.y = f2bf(src[(size_t)(c + 1) * lv.HW]);
        pk.z = f2bf(src[(size_t)(c + 2) * lv.HW]);
        pk.w = f2bf(src[(size_t)(c + 3) * lv.HW]);
        *(ushort4*)(dst + (size_t)(c >> 5) * lv.PP * 32 +
                    (size_t)pp * 32 + (c & 31)) = pk;
    }
}

// ---------------------------------------------------------------------------
// tower weights: [br][layer][tap][kb][co 256][32ci]. Coalesced: one thread
// per (br,layer,co,ci) reads its 9 taps contiguously (36B/thread).
__global__ __launch_bounds__(256) void prepwt_k(
    const float* __restrict__ cw, const float* __restrict__ rw,
    unsigned short* __restrict__ dst)
{
    const int idx = blockIdx.x * 256 + threadIdx.x;   // 2*3*256*256 threads
    const int ci = idx & 255, co = (idx >> 8) & 255;
    const int lyr = (idx >> 16) % 3, br = idx / (65536 * 3);
    const float* s = br ? rw : cw;
    const float* sp = s + (((size_t)lyr * 256 + co) * 256 + ci) * 9;
    float v[9];
#pragma unroll
    for (int t = 0; t < 9; ++t) v[t] = sp[t];
    unsigned short* dp = dst + ((size_t)br * 27 + lyr * 9) * 65536 +
                         (size_t)(((ci >> 5) * 256 + co) * 32) + (ci & 31);
#pragma unroll
    for (int t = 0; t < 9; ++t) dp[(size_t)t * 65536] = f2bf(v[t]);
}

// head weights: [tap][kb][co rows][32ci], rows=256 (zero-padded planes)
__global__ __launch_bounds__(256) void prepwh_k(
    const float* __restrict__ src, unsigned short* __restrict__ dst,
    int CO, int rows, int roff)
{
    const int idx = blockIdx.x * 256 + threadIdx.x;
    if (idx >= CO * 2304) return;
    const int ci = idx & 255, rr = idx >> 8;
    const int tap = rr % 9, co = rr / 9;
    dst[((size_t)(tap * 8 + (ci >> 5)) * rows + roff + co) * 32 + (ci & 31)] =
        f2bf(src[((size_t)co * 256 + ci) * 9 + tap]);
}

// ---------------------------------------------------------------------------
extern "C" void kernel_launch(void* const* d_in, const int* in_sizes, int n_in,
                              void* d_out, int out_size, void* d_ws, size_t ws_size,
                              hipStream_t stream) {
    const float* f0 = (const float*)d_in[0];
    const float* f1 = (const float*)d_in[1];
    const float* f2 = (const float*)d_in[2];
    const float* f3 = (const float*)d_in[3];
    const float* f4 = (const float*)d_in[4];
    const float* cls_w  = (const float*)d_in[5];
    const float* cls_b  = (const float*)d_in[6];
    const float* cls_g  = (const float*)d_in[7];
    const float* cls_be = (const float*)d_in[8];
    const float* log_w  = (const float*)d_in[9];
    const float* log_b  = (const float*)d_in[10];
    const float* reg_w  = (const float*)d_in[11];
    const float* reg_b  = (const float*)d_in[12];
    const float* reg_g  = (const float*)d_in[13];
    const float* reg_be = (const float*)d_in[14];
    const float* bbox_w = (const float*)d_in[15];
    const float* bbox_b = (const float*)d_in[16];
    const float* ctr_w  = (const float*)d_in[17];
    const float* ctr_b  = (const float*)d_in[18];
    float* out = (float*)d_out;

    Tab tb;
    // t_conv: 128-pos tiles over PADDED pp space: ceil(PP/128) =
    // 104,27,8,3,1 -> cum 0,104,131,139,142 (NT=143).
    //            t_conv t_gn t_prep t_h5 xo       P2W  PP     HW     W    H   lwW loff
    tb.lv[0] = {   0,    0,    0,    0,   0,       130, 13260, 12800, 128, 100, 7, 0     };
    tb.lv[1] = { 104,  400,  200,  52,  6789120,    66,  3432,  3200,  64,  50, 6, 12800 };
    tb.lv[2] = { 131,  500,  250,  66,  8546304,    34,   918,   800,  32,  25, 5, 16000 };
    tb.lv[3] = { 139,  525,  263,  70,  9016320,    18,   270,   208,  16,  13, 4, 16800 };
    tb.lv[4] = { 142,  532,  267,  72,  9154560,    10,    90,    56,   8,   7, 3, 17008 };
    const int NT_CONV = 143, NT_GN = 534, NT_PREP = 268;
    const size_t XEL = 9200640;
    const size_t WHP = (size_t)72 * 256 * 32;     // one 256-row head weight plane

    char* base = (char*)d_ws;
    size_t o = 0;
    auto take = [&](size_t bytes) {
        char* p = base + o; o += (bytes + 255) & ~(size_t)255; return p;
    };
    take(131072);                                        // guard 128KB
    unsigned short* PX = (unsigned short*)take(XEL * 2);          // shared input
    take(131072);
    unsigned short* B1 = (unsigned short*)take(XEL * 2 * 2);      // [br]
    take(131072);
    unsigned short* B2 = (unsigned short*)take(XEL * 2 * 2);      // [br]
    take(131072);
    unsigned short* WT = (unsigned short*)take((size_t)54 * 65536 * 2);
    unsigned short* WH = (unsigned short*)take(WHP * 2 * 2);      // [br] planes
    float* ST  = (float*)take(1920 * 4);
    float* RB5 = (float*)take(32);

    hipMemsetAsync(PX, 0, XEL * 2, stream);
    hipMemsetAsync(B1, 0, XEL * 4, stream);
    hipMemsetAsync(B2, 0, XEL * 4, stream);
    hipMemsetAsync(ST, 0, 1920 * 4, stream);
    hipMemsetAsync(WH, 0, WHP * 2 * 2, stream);
    hipMemcpyAsync(RB5,     bbox_b, 4 * 4, hipMemcpyDeviceToDevice, stream);
    hipMemcpyAsync(RB5 + 4, ctr_b,  1 * 4, hipMemcpyDeviceToDevice, stream);

    prepwt_k<<<dim3(1536), dim3(256), 0, stream>>>(cls_w, reg_w, WT);
    prepwh_k<<<dim3(720), dim3(256), 0, stream>>>(log_w,  WH,       80, 256, 0);
    prepwh_k<<<dim3(36),  dim3(256), 0, stream>>>(bbox_w, WH + WHP,  4, 256, 0);
    prepwh_k<<<dim3(9),   dim3(256), 0, stream>>>(ctr_w,  WH + WHP,  1, 256, 4);

    prepx_k<<<dim3(NT_PREP, 1, 2), dim3(256), 0, stream>>>(f0, f1, f2, f3, f4, PX, tb);

    // chain: conv0 PX->B1[br], gn0 B1; conv1 B1->B2, gn1 B2; conv2 B2->B1,
    // gn2 B1; fused head (z=4): br=0 cls from B1[0], br=1 bbox+ctr from B1[1].
    const size_t WBRS = (size_t)27 * 65536;
    unsigned short* cin[3]  = {PX, B1, B2};
    size_t          cbrs[3] = {0, XEL, XEL};
    unsigned short* cout_[3] = {B1, B2, B1};
    for (int i = 0; i < 3; ++i) {
        conv_k<0><<<dim3(NT_CONV, 1, 4), dim3(256), 0, stream>>>(
            cin[i], cbrs[i], WT + (size_t)i * 9 * 65536, WBRS, 256,
            cls_b + i * 256, reg_b + i * 256,
            cout_[i], ST, i, nullptr, tb);
        gn_k<<<dim3(NT_GN, 1, 4), dim3(256), 0, stream>>>(
            cout_[i], ST, i, cls_g, cls_be, reg_g, reg_be, tb);
    }
    conv_k<1><<<dim3(NT_CONV, 1, 4), dim3(256), 0, stream>>>(
        B1, XEL, WH, WHP, 256, log_b, RB5,
        nullptr, nullptr, 0, out, tb);
}

// Round 13
// 862.131 us; speedup vs baseline: 1.1245x; 1.0451x over previous
//
#include <hip/hip_runtime.h>

#define NCLS 80
#define TPOINTS 17064
#define GN_EPS 1e-5f

typedef float v4f __attribute__((ext_vector_type(4)));
typedef short v8s __attribute__((ext_vector_type(8)));

__device__ __forceinline__ unsigned short f2bf(float f) {
    unsigned u = __float_as_uint(f);
    unsigned r = (u + 0x7FFFu + ((u >> 16) & 1u)) >> 16;
    return (unsigned short)r;
}
__device__ __forceinline__ float bf2f(unsigned short h) {
    return __uint_as_float(((unsigned)h) << 16);
}
__device__ __forceinline__ void gload16(const unsigned short* g, unsigned short* l) {
    __builtin_amdgcn_global_load_lds(
        (const __attribute__((address_space(1))) unsigned int*)g,
        (__attribute__((address_space(3))) unsigned int*)l, 16, 0, 0);
}
template<int N> __device__ __forceinline__ void vwait() {
    asm volatile("s_waitcnt vmcnt(%0)" :: "n"(N) : "memory");
    __builtin_amdgcn_sched_barrier(0);
}
#define LGKM0 do { asm volatile("s_waitcnt lgkmcnt(0)" ::: "memory"); \
                   __builtin_amdgcn_sched_barrier(0); } while (0)

struct Lv { int t_conv, t_gn, t_prep, t_h5, xo, P2W, PP, HW, W, H, lwW, loff; };
struct Tab { Lv lv[5]; };

// ---------------------------------------------------------------------------
// TOWER conv (r12, passing, verbatim): 256co x 128pos, 4 FAT waves
// (128co x 64pos, acc[8][4]); 3-deep pipeline; LDS 72KB -> 2 blocks/CU;
// 6 gloads/wave/half; vwait<12>/<6>/<0>; r8 half-body order; XOR swizzle.
// bf16 ci-blocked out + fused GN stats. 196.5us measured, occupancy 14.4%
// == exact 2-round packing model (572 items / 512 slots).
// ---------------------------------------------------------------------------
__global__ __launch_bounds__(256, 2) void conv_k(
    const unsigned short* __restrict__ xin, size_t xin_brs,
    const unsigned short* __restrict__ wt, size_t wt_brs, int wrows,
    const float* __restrict__ bias_c, const float* __restrict__ bias_r,
    unsigned short* __restrict__ yout, float* __restrict__ stats, int layer,
    Tab tb)
{
    __shared__ __align__(16) unsigned short sA[3 * 256 * 32];   // 48KB
    __shared__ __align__(16) unsigned short sB[3 * 128 * 32];   // 24KB
    const int tid = threadIdx.x, lane = tid & 63, wave = tid >> 6;
    const int bx = blockIdx.x, z = blockIdx.z;
    const int n = z & 1, br = z >> 1;
    int L = 0;
    while (L < 4 && bx >= tb.lv[L + 1].t_conv) ++L;
    const Lv lv = tb.lv[L];
    const int pp0 = (bx - lv.t_conv) * 128;
    const size_t XELs = 9200640;
    const size_t PP32 = (size_t)lv.PP * 32;

    v4f acc[8][4];
#pragma unroll
    for (int i = 0; i < 8; ++i)
#pragma unroll
        for (int j = 0; j < 4; ++j) acc[i][j] = (v4f)0.f;

    const unsigned short* wtb = wt + (size_t)br * wt_brs;
    const float* bias = br ? bias_r : bias_c;
    const unsigned short* xb = xin + (size_t)br * xin_brs +
                               (size_t)lv.xo + (size_t)n * lv.PP * 256;

    const int lr = lane >> 2;
    const int lc = ((lane & 3) ^ ((lane >> 3) & 3)) * 8;
    const unsigned short* ag = wtb + (size_t)(wave * 64 + lr) * 32 + lc;
    const unsigned short* bgh = xb + (ptrdiff_t)(pp0 + wave * 32 + lr) * 32 + lc;
    unsigned short* laW = &sA[wave * 64 * 32];
    unsigned short* lbW = &sB[wave * 32 * 32];
    const size_t wstride2 = (size_t)wrows * 32;

    const int col = lane & 15, q = lane >> 4;
    const int wr = wave & 1, wc = wave >> 1;
    const int qs = (q ^ ((col >> 1) & 3)) << 3;
    int ard[8], brd[4];
#pragma unroll
    for (int i = 0; i < 8; ++i) ard[i] = (wr * 128 + i * 16 + col) * 32 + qs;
#pragma unroll
    for (int j = 0; j < 4; ++j) brd[j] = (wc * 64 + j * 16 + col) * 32 + qs;

    auto stageHalf = [&](int s) {
        const int slot = s % 3;
        const unsigned short* at = ag + (size_t)s * wstride2;
        gload16(at,        laW + slot * 8192);
        gload16(at + 512,  laW + slot * 8192 + 512);
        gload16(at + 1024, laW + slot * 8192 + 1024);
        gload16(at + 1536, laW + slot * 8192 + 1536);
        const int t = s >> 3, kb = s & 7;
        const ptrdiff_t goff = ((ptrdiff_t)(t / 3) - 1) * lv.P2W + (t % 3) - 1;
        const unsigned short* bt = bgh + (size_t)kb * PP32 + goff * 32;
        gload16(bt,       lbW + slot * 4096);
        gload16(bt + 512, lbW + slot * 4096 + 512);
    };

    auto half_body = [&](int h, bool dostage) {
        const int sa = (h % 3) * 8192, sb_ = (h % 3) * 4096;
        v8s af[8], bfr[4];
#pragma unroll
        for (int i = 0; i < 8; ++i) af[i]  = *(const v8s*)&sA[sa + ard[i]];
#pragma unroll
        for (int j = 0; j < 4; ++j) bfr[j] = *(const v8s*)&sB[sb_ + brd[j]];
        LGKM0;
        __builtin_amdgcn_s_barrier();
        if (dostage) stageHalf(h + 3);
        __builtin_amdgcn_sched_barrier(0);
        __builtin_amdgcn_s_setprio(1);
#pragma unroll
        for (int i = 0; i < 8; ++i)
#pragma unroll
            for (int j = 0; j < 4; ++j)
                acc[i][j] = __builtin_amdgcn_mfma_f32_16x16x32_bf16(
                    af[i], bfr[j], acc[i][j], 0, 0, 0);
        __builtin_amdgcn_s_setprio(0);
    };

    stageHalf(0); stageHalf(1); stageHalf(2);
#pragma unroll 1
    for (int h = 0; h < 70; ++h) {
        vwait<12>();
        __builtin_amdgcn_s_barrier();
        half_body(h, h < 69);
    }
    vwait<6>(); __builtin_amdgcn_s_barrier(); half_body(70, false);
    vwait<0>(); __builtin_amdgcn_s_barrier(); half_body(71, false);

    unsigned short* yb = yout + (size_t)br * XELs + (size_t)lv.xo +
                         (size_t)n * lv.PP * 256;
    const int slot = br * 3 + layer;
#pragma unroll
    for (int i = 0; i < 8; ++i) {
        const int cobase = wr * 128 + i * 16 + q * 4;
        const float4 b4 = *(const float4*)(bias + cobase);
        const size_t kbo = (size_t)(cobase >> 5) * PP32;
        const int cc = cobase & 31;
        float s = 0.f, ss = 0.f;
#pragma unroll
        for (int j = 0; j < 4; ++j) {
            const int pp = pp0 + wc * 64 + j * 16 + col;
            const unsigned h2 = (unsigned)pp / (unsigned)lv.P2W;
            const unsigned w2 = (unsigned)pp - h2 * lv.P2W;
            const bool in = (h2 >= 1u) & (h2 <= (unsigned)lv.H) &
                            (w2 >= 1u) & (w2 <= (unsigned)lv.W);
            float v0 = acc[i][j][0] + b4.x;
            float v1 = acc[i][j][1] + b4.y;
            float v2 = acc[i][j][2] + b4.z;
            float v3 = acc[i][j][3] + b4.w;
            if (in) {
                ushort4 pk;
                pk.x = f2bf(v0); pk.y = f2bf(v1);
                pk.z = f2bf(v2); pk.w = f2bf(v3);
                *(ushort4*)(yb + kbo + (size_t)pp * 32 + cc) = pk;
                s  += v0 + v1 + v2 + v3;
                ss += v0 * v0 + v1 * v1 + v2 * v2 + v3 * v3;
            }
        }
#pragma unroll
        for (int o = 32; o > 0; o >>= 1) {
            s  += __shfl_down(s, o, 64);
            ss += __shfl_down(ss, o, 64);
        }
        if (lane == 0) {
            const int g = cobase >> 4;
            const int si = (((slot * 5 + L) * 32) + n * 16 + g) * 2;
            atomicAdd(&stats[si + 0], s);
            atomicAdd(&stats[si + 1], ss);
        }
    }
}

// ---------------------------------------------------------------------------
// HEAD conv (r13 NEW): 128co x 128pos, 4 THIN waves (2co x 2pos, 64x64,
// acc[4][4]=64 AGPR, ~134 regs -> 3 waves/SIMD); 3-deep pipeline; LDS
// 2x24KB=48KB -> 3 BLOCKS/CU = 768 slots >= 572 items -> SINGLE ROUND
// (was 2 rounds at 256co/2 blocks). Coverage: cls needs 80<=128 cols
// (br=0, B1[0]), reg needs 5 (br=1, B1[1]) -> one 128co tile each.
// 4 gloads/wave/half (2A+2B, uniform) -> vwait<8>/<4>/<0>. r8 half-body
// order. fp32 strided out: br0 cols 0-79; br1 cols 80-84, relu co<4.
// ---------------------------------------------------------------------------
__global__ __launch_bounds__(256, 3) void head_k(
    const unsigned short* __restrict__ xin, size_t xin_brs,
    const unsigned short* __restrict__ wt, size_t wt_brs,
    const float* __restrict__ bias_c, const float* __restrict__ bias_r,
    float* __restrict__ out, Tab tb)
{
    __shared__ __align__(16) unsigned short sA[3 * 128 * 32];   // 24KB
    __shared__ __align__(16) unsigned short sB[3 * 128 * 32];   // 24KB
    const int tid = threadIdx.x, lane = tid & 63, wave = tid >> 6;
    const int bx = blockIdx.x, z = blockIdx.z;
    const int n = z & 1, br = z >> 1;
    int L = 0;
    while (L < 4 && bx >= tb.lv[L + 1].t_conv) ++L;
    const Lv lv = tb.lv[L];
    const int pp0 = (bx - lv.t_conv) * 128;
    const size_t PP32 = (size_t)lv.PP * 32;

    v4f acc[4][4];
#pragma unroll
    for (int i = 0; i < 4; ++i)
#pragma unroll
        for (int j = 0; j < 4; ++j) acc[i][j] = (v4f)0.f;

    const unsigned short* wtb = wt + (size_t)br * wt_brs;
    const float* bias = br ? bias_r : bias_c;
    const unsigned short* xb = xin + (size_t)br * xin_brs +
                               (size_t)lv.xo + (size_t)n * lv.PP * 256;

    // A: wave w rows [w*32,+32) of 128 (2 gloads); B: same split (2 gloads).
    const int lr = lane >> 2;
    const int lc = ((lane & 3) ^ ((lane >> 3) & 3)) * 8;
    const unsigned short* ag = wtb + (size_t)(wave * 32 + lr) * 32 + lc;
    const unsigned short* bgh = xb + (ptrdiff_t)(pp0 + wave * 32 + lr) * 32 + lc;
    unsigned short* laW = &sA[wave * 32 * 32];
    unsigned short* lbW = &sB[wave * 32 * 32];
    const size_t wstride2 = (size_t)256 * 32;     // head weight rows = 256

    const int col = lane & 15, q = lane >> 4;
    const int wr = wave & 1, wc = wave >> 1;      // 2 co-halves x 2 pos-halves
    const int qs = (q ^ ((col >> 1) & 3)) << 3;
    int ard[4], brd[4];
#pragma unroll
    for (int i = 0; i < 4; ++i) ard[i] = (wr * 64 + i * 16 + col) * 32 + qs;
#pragma unroll
    for (int j = 0; j < 4; ++j) brd[j] = (wc * 64 + j * 16 + col) * 32 + qs;

    auto stageHalf = [&](int s) {
        const int slot = s % 3;
        const unsigned short* at = ag + (size_t)s * wstride2;
        gload16(at,       laW + slot * 4096);
        gload16(at + 512, laW + slot * 4096 + 512);
        const int t = s >> 3, kb = s & 7;
        const ptrdiff_t goff = ((ptrdiff_t)(t / 3) - 1) * lv.P2W + (t % 3) - 1;
        const unsigned short* bt = bgh + (size_t)kb * PP32 + goff * 32;
        gload16(bt,       lbW + slot * 4096);
        gload16(bt + 512, lbW + slot * 4096 + 512);
    };

    auto half_body = [&](int h, bool dostage) {
        const int sa = (h % 3) * 4096, sb_ = (h % 3) * 4096;
        v8s af[4], bfr[4];
#pragma unroll
        for (int i = 0; i < 4; ++i) af[i]  = *(const v8s*)&sA[sa + ard[i]];
#pragma unroll
        for (int j = 0; j < 4; ++j) bfr[j] = *(const v8s*)&sB[sb_ + brd[j]];
        LGKM0;
        __builtin_amdgcn_s_barrier();
        if (dostage) stageHalf(h + 3);
        __builtin_amdgcn_sched_barrier(0);
        __builtin_amdgcn_s_setprio(1);
#pragma unroll
        for (int i = 0; i < 4; ++i)
#pragma unroll
            for (int j = 0; j < 4; ++j)
                acc[i][j] = __builtin_amdgcn_mfma_f32_16x16x32_bf16(
                    af[i], bfr[j], acc[i][j], 0, 0, 0);
        __builtin_amdgcn_s_setprio(0);
    };

    stageHalf(0); stageHalf(1); stageHalf(2);
#pragma unroll 1
    for (int h = 0; h < 70; ++h) {
        vwait<8>();
        __builtin_amdgcn_s_barrier();
        half_body(h, h < 69);
    }
    vwait<4>(); __builtin_amdgcn_s_barrier(); half_body(70, false);
    vwait<0>(); __builtin_amdgcn_s_barrier(); half_body(71, false);

    // br=0: cls logits, CO=80, out cols 0..79, no relu.
    // br=1: bbox+ctr, CO=5, out cols 80..84, relu co<4.
    const int CO_ = br ? 5 : 80;
    const int coo = br ? 80 : 0;
    const int rel = br ? 4 : 0;
#pragma unroll
    for (int i = 0; i < 4; ++i) {
        const int cobase = wr * 64 + i * 16 + q * 4;
        float bv[4];
#pragma unroll
        for (int k = 0; k < 4; ++k)
            bv[k] = (cobase + k < CO_) ? bias[cobase + k] : 0.f;
#pragma unroll
        for (int j = 0; j < 4; ++j) {
            const int pp = pp0 + wc * 64 + j * 16 + col;
            const unsigned h2 = (unsigned)pp / (unsigned)lv.P2W;
            const unsigned w2 = (unsigned)pp - h2 * lv.P2W;
            const bool in = (h2 >= 1u) & (h2 <= (unsigned)lv.H) &
                            (w2 >= 1u) & (w2 <= (unsigned)lv.W);
            if (in) {
                const int p = (h2 - 1) * lv.W + (w2 - 1);
                float* ob = out + ((size_t)n * TPOINTS + lv.loff + p) * 85 + coo;
#pragma unroll
                for (int k = 0; k < 4; ++k) {
                    const int co = cobase + k;
                    if (co < CO_) {
                        float v = acc[i][j][k] + bv[k];
                        if (co < rel) v = fmaxf(v, 0.f);
                        ob[co] = v;
                    }
                }
            }
        }
    }
}

// ---------------------------------------------------------------------------
// GN + affine + ReLU, in-place, fused across levels AND branches (z=br*2+n).
// ---------------------------------------------------------------------------
__global__ __launch_bounds__(256) void gn_k(
    unsigned short* __restrict__ x, const float* __restrict__ stats, int layer,
    const float* __restrict__ g_c, const float* __restrict__ be_c,
    const float* __restrict__ g_r, const float* __restrict__ be_r, Tab tb)
{
    const int tid = threadIdx.x, bx = blockIdx.x, z = blockIdx.z;
    const int n = z & 1, br = z >> 1;
    const size_t XELs = 9200640;
    int L = 0;
    while (L < 4 && bx >= tb.lv[L + 1].t_gn) ++L;
    const Lv lv = tb.lv[L];
    const int pos = (bx - lv.t_gn) * 32 + (tid >> 3);
    if (pos >= lv.HW) return;
    const int slot = br * 3 + layer;
    const float* gamma = (br ? g_r : g_c) + layer * 256;
    const float* beta  = (br ? be_r : be_c) + layer * 256;
    const int c0 = (tid & 7) * 32;
    const int h = pos >> lv.lwW, w = pos & (lv.W - 1);
    const int pp = (h + 1) * lv.P2W + (w + 1);
    unsigned short* p = x + (size_t)br * XELs + (size_t)lv.xo +
                        (size_t)n * lv.PP * 256 +
                        (size_t)(tid & 7) * lv.PP * 32 + (size_t)pp * 32;
    const float inv = 1.0f / (16.0f * (float)lv.HW);
    const int sb = ((slot * 5 + L) * 32 + n * 16) * 2;

    float scv[32], shv[32];
#pragma unroll
    for (int gg = 0; gg < 2; ++gg) {
        const int g = (c0 >> 4) + gg;
        const float mm = stats[sb + g * 2 + 0] * inv;
        const float v = stats[sb + g * 2 + 1] * inv - mm * mm;
        const float rs = rsqrtf(v + GN_EPS);
#pragma unroll
        for (int k = 0; k < 16; ++k) {
            const int c = g * 16 + k;
            const float sc = rs * gamma[c];
            scv[gg * 16 + k] = sc;
            shv[gg * 16 + k] = beta[c] - mm * sc;
        }
    }
#pragma unroll
    for (int u = 0; u < 4; ++u) {
        uint4 a = *(const uint4*)(p + u * 8);
        unsigned wds[4] = {a.x, a.y, a.z, a.w};
#pragma unroll
        for (int k = 0; k < 4; ++k) {
            const int e = u * 8 + k * 2;
            float lo = bf2f((unsigned short)(wds[k] & 0xffffu));
            float hi = bf2f((unsigned short)(wds[k] >> 16));
            lo = fmaxf(lo * scv[e]     + shv[e],     0.f);
            hi = fmaxf(hi * scv[e + 1] + shv[e + 1], 0.f);
            wds[k] = (unsigned)f2bf(lo) | ((unsigned)f2bf(hi) << 16);
        }
        uint4 o; o.x = wds[0]; o.y = wds[1]; o.z = wds[2]; o.w = wds[3];
        *(uint4*)(p + u * 8) = o;
    }
}

// ---------------------------------------------------------------------------
// fp32 NCHW feats -> bf16 ci-blocked padded interior.
// ---------------------------------------------------------------------------
__global__ __launch_bounds__(256) void prepx_k(
    const float* f0, const float* f1, const float* f2, const float* f3,
    const float* f4, unsigned short* __restrict__ xo, Tab tb)
{
    const float* fs[5] = {f0, f1, f2, f3, f4};
    const int tid = threadIdx.x, bx = blockIdx.x, n = blockIdx.z;
    int L = 0;
    while (L < 4 && bx >= tb.lv[L + 1].t_prep) ++L;
    const Lv lv = tb.lv[L];
    const int pos = (bx - lv.t_prep) * 64 + (tid & 63);
    const int wave = tid >> 6;
    if (pos >= lv.HW) return;
    const int h = pos >> lv.lwW, w = pos & (lv.W - 1);
    const int pp = (h + 1) * lv.P2W + (w + 1);
    const float* src = fs[L] + (size_t)n * 256 * lv.HW + pos;
    unsigned short* dst = xo + (size_t)lv.xo + (size_t)n * lv.PP * 256;
#pragma unroll
    for (int k = 0; k < 16; ++k) {
        const int c = wave * 64 + k * 4;
        ushort4 pk;
        pk.x = f2bf(src[(size_t)(c + 0) * lv.HW]);
        pk.y = f2bf(src[(size_t)(c + 1) * lv.HW]);
        pk.z = f2bf(src[(size_t)(c + 2) * lv.HW]);
        pk.w = f2bf(src[(size_t)(c + 3) * lv.HW]);
        *(ushort4*)(dst + (size_t)(c >> 5) * lv.PP * 32 +
                    (size_t)pp * 32 + (c & 31)) = pk;
    }
}

// ---------------------------------------------------------------------------
// tower weights: [br][layer][tap][kb][co 256][32ci]. Coalesced: one thread
// per (br,layer,co,ci) reads its 9 taps contiguously (36B/thread).
__global__ __launch_bounds__(256) void prepwt_k(
    const float* __restrict__ cw, const float* __restrict__ rw,
    unsigned short* __restrict__ dst)
{
    const int idx = blockIdx.x * 256 + threadIdx.x;   // 2*3*256*256 threads
    const int ci = idx & 255, co = (idx >> 8) & 255;
    const int lyr = (idx >> 16) % 3, br = idx / (65536 * 3);
    const float* s = br ? rw : cw;
    const float* sp = s + (((size_t)lyr * 256 + co) * 256 + ci) * 9;
    float v[9];
#pragma unroll
    for (int t = 0; t < 9; ++t) v[t] = sp[t];
    unsigned short* dp = dst + ((size_t)br * 27 + lyr * 9) * 65536 +
                         (size_t)(((ci >> 5) * 256 + co) * 32) + (ci & 31);
#pragma unroll
    for (int t = 0; t < 9; ++t) dp[(size_t)t * 65536] = f2bf(v[t]);
}

// head weights: [tap][kb][co rows][32ci], rows=256 (zero-padded planes)
__global__ __launch_bounds__(256) void prepwh_k(
    const float* __restrict__ src, unsigned short* __restrict__ dst,
    int CO, int rows, int roff)
{
    const int idx = blockIdx.x * 256 + threadIdx.x;
    if (idx >= CO * 2304) return;
    const int ci = idx & 255, rr = idx >> 8;
    const int tap = rr % 9, co = rr / 9;
    dst[((size_t)(tap * 8 + (ci >> 5)) * rows + roff + co) * 32 + (ci & 31)] =
        f2bf(src[((size_t)co * 256 + ci) * 9 + tap]);
}

// ---------------------------------------------------------------------------
extern "C" void kernel_launch(void* const* d_in, const int* in_sizes, int n_in,
                              void* d_out, int out_size, void* d_ws, size_t ws_size,
                              hipStream_t stream) {
    const float* f0 = (const float*)d_in[0];
    const float* f1 = (const float*)d_in[1];
    const float* f2 = (const float*)d_in[2];
    const float* f3 = (const float*)d_in[3];
    const float* f4 = (const float*)d_in[4];
    const float* cls_w  = (const float*)d_in[5];
    const float* cls_b  = (const float*)d_in[6];
    const float* cls_g  = (const float*)d_in[7];
    const float* cls_be = (const float*)d_in[8];
    const float* log_w  = (const float*)d_in[9];
    const float* log_b  = (const float*)d_in[10];
    const float* reg_w  = (const float*)d_in[11];
    const float* reg_b  = (const float*)d_in[12];
    const float* reg_g  = (const float*)d_in[13];
    const float* reg_be = (const float*)d_in[14];
    const float* bbox_w = (const float*)d_in[15];
    const float* bbox_b = (const float*)d_in[16];
    const float* ctr_w  = (const float*)d_in[17];
    const float* ctr_b  = (const float*)d_in[18];
    float* out = (float*)d_out;

    Tab tb;
    // t_conv: 128-pos tiles over PADDED pp space: ceil(PP/128) =
    // 104,27,8,3,1 -> cum 0,104,131,139,142 (NT=143).
    //            t_conv t_gn t_prep t_h5 xo       P2W  PP     HW     W    H   lwW loff
    tb.lv[0] = {   0,    0,    0,    0,   0,       130, 13260, 12800, 128, 100, 7, 0     };
    tb.lv[1] = { 104,  400,  200,  52,  6789120,    66,  3432,  3200,  64,  50, 6, 12800 };
    tb.lv[2] = { 131,  500,  250,  66,  8546304,    34,   918,   800,  32,  25, 5, 16000 };
    tb.lv[3] = { 139,  525,  263,  70,  9016320,    18,   270,   208,  16,  13, 4, 16800 };
    tb.lv[4] = { 142,  532,  267,  72,  9154560,    10,    90,    56,   8,   7, 3, 17008 };
    const int NT_CONV = 143, NT_GN = 534, NT_PREP = 268;
    const size_t XEL = 9200640;
    const size_t WHP = (size_t)72 * 256 * 32;     // one 256-row head weight plane

    char* base = (char*)d_ws;
    size_t o = 0;
    auto take = [&](size_t bytes) {
        char* p = base + o; o += (bytes + 255) & ~(size_t)255; return p;
    };
    take(131072);                                        // guard 128KB
    unsigned short* PX = (unsigned short*)take(XEL * 2);          // shared input
    take(131072);
    unsigned short* B1 = (unsigned short*)take(XEL * 2 * 2);      // [br]
    take(131072);
    unsigned short* B2 = (unsigned short*)take(XEL * 2 * 2);      // [br]
    take(131072);
    unsigned short* WT = (unsigned short*)take((size_t)54 * 65536 * 2);
    unsigned short* WH = (unsigned short*)take(WHP * 2 * 2);      // [br] planes
    float* ST  = (float*)take(1920 * 4);
    float* RB5 = (float*)take(32);

    hipMemsetAsync(PX, 0, XEL * 2, stream);
    hipMemsetAsync(B1, 0, XEL * 4, stream);
    hipMemsetAsync(B2, 0, XEL * 4, stream);
    hipMemsetAsync(ST, 0, 1920 * 4, stream);
    hipMemsetAsync(WH, 0, WHP * 2 * 2, stream);
    hipMemcpyAsync(RB5,     bbox_b, 4 * 4, hipMemcpyDeviceToDevice, stream);
    hipMemcpyAsync(RB5 + 4, ctr_b,  1 * 4, hipMemcpyDeviceToDevice, stream);

    prepwt_k<<<dim3(1536), dim3(256), 0, stream>>>(cls_w, reg_w, WT);
    prepwh_k<<<dim3(720), dim3(256), 0, stream>>>(log_w,  WH,       80, 256, 0);
    prepwh_k<<<dim3(36),  dim3(256), 0, stream>>>(bbox_w, WH + WHP,  4, 256, 0);
    prepwh_k<<<dim3(9),   dim3(256), 0, stream>>>(ctr_w,  WH + WHP,  1, 256, 4);

    prepx_k<<<dim3(NT_PREP, 1, 2), dim3(256), 0, stream>>>(f0, f1, f2, f3, f4, PX, tb);

    // chain: conv0 PX->B1[br], gn0 B1; conv1 B1->B2, gn1 B2; conv2 B2->B1,
    // gn2 B1; head (z=4, 128co single round): br=0 cls from B1[0],
    // br=1 bbox+ctr from B1[1].
    const size_t WBRS = (size_t)27 * 65536;
    unsigned short* cin[3]  = {PX, B1, B2};
    size_t          cbrs[3] = {0, XEL, XEL};
    unsigned short* cout_[3] = {B1, B2, B1};
    for (int i = 0; i < 3; ++i) {
        conv_k<<<dim3(NT_CONV, 1, 4), dim3(256), 0, stream>>>(
            cin[i], cbrs[i], WT + (size_t)i * 9 * 65536, WBRS, 256,
            cls_b + i * 256, reg_b + i * 256,
            cout_[i], ST, i, tb);
        gn_k<<<dim3(NT_GN, 1, 4), dim3(256), 0, stream>>>(
            cout_[i], ST, i, cls_g, cls_be, reg_g, reg_be, tb);
    }
    head_k<<<dim3(NT_CONV, 1, 4), dim3(256), 0, stream>>>(
        B1, XEL, WH, WHP, log_b, RB5, out, tb);
}